// Round 1
// baseline (64.648 us; speedup 1.0000x reference)
//
#include <hip/hip_runtime.h>

// FM forward on MI355X.
// Shapes: x_num (8192,3) f32, x_cat (8192,4) i32, v (18183,16) f32,
// global_bias (1,) f32, num_bias (3,) f32, cat_bias (18180,) f32.
// Output: (8192,1) f32.
//
// Math per row b:
//   idx_j = x_cat[b,j] + offset_j, offsets = {0,10000,18000,18100}
//   bias  = gb + sum_j xn_j*nb_j + sum_j cbias[idx_j]
//   s[e]  = sum_j xn_j * v[j,e] + sum_j v[3+idx_j, e]      (j<3 numeric, j<4 cat)
//   ss[e] = sum_j (xn_j*v[j,e])^2 + sum_j v[3+idx_j,e]^2
//   y = bias + 0.5 * sum_e (s[e]^2 - ss[e])

#define FM_BATCH 8192
#define FM_EMB   16

__global__ __launch_bounds__(64) void fm_fwd_kernel(
    const float* __restrict__ x_num,
    const int*   __restrict__ x_cat,
    const float* __restrict__ v,
    const float* __restrict__ gbias,
    const float* __restrict__ nbias,
    const float* __restrict__ cbias,
    float*       __restrict__ out)
{
    const int b = blockIdx.x * blockDim.x + threadIdx.x;
    if (b >= FM_BATCH) return;

    const float xn0 = x_num[b * 3 + 0];
    const float xn1 = x_num[b * 3 + 1];
    const float xn2 = x_num[b * 3 + 2];

    const int i0 = x_cat[b * 4 + 0];           // + 0
    const int i1 = x_cat[b * 4 + 1] + 10000;
    const int i2 = x_cat[b * 4 + 2] + 18000;
    const int i3 = x_cat[b * 4 + 3] + 18100;

    float bias = gbias[0]
               + xn0 * nbias[0] + xn1 * nbias[1] + xn2 * nbias[2]
               + cbias[i0] + cbias[i1] + cbias[i2] + cbias[i3];

    // v rows as float4 quads: row r, quad q -> v4[r*4 + q]
    const float4* __restrict__ v4 = reinterpret_cast<const float4*>(v);
    const long r0 = (long)(3 + i0) * 4;
    const long r1 = (long)(3 + i1) * 4;
    const long r2 = (long)(3 + i2) * 4;
    const long r3 = (long)(3 + i3) * 4;

    float acc = 0.0f;
#pragma unroll
    for (int q = 0; q < 4; ++q) {
        const float4 a0 = v4[0 * 4 + q];   // numeric rows (shared -> L1/L2 hit)
        const float4 a1 = v4[1 * 4 + q];
        const float4 a2 = v4[2 * 4 + q];
        const float4 c0 = v4[r0 + q];
        const float4 c1 = v4[r1 + q];
        const float4 c2 = v4[r2 + q];
        const float4 c3 = v4[r3 + q];

#define FM_COMP(f)                                                          \
        {                                                                   \
            const float t0 = xn0 * a0.f, t1 = xn1 * a1.f, t2 = xn2 * a2.f;  \
            const float s  = t0 + t1 + t2 + c0.f + c1.f + c2.f + c3.f;      \
            const float ss = t0 * t0 + t1 * t1 + t2 * t2                    \
                           + c0.f * c0.f + c1.f * c1.f                      \
                           + c2.f * c2.f + c3.f * c3.f;                     \
            acc += s * s - ss;                                              \
        }
        FM_COMP(x)
        FM_COMP(y)
        FM_COMP(z)
        FM_COMP(w)
#undef FM_COMP
    }

    out[b] = bias + 0.5f * acc;
}

extern "C" void kernel_launch(void* const* d_in, const int* in_sizes, int n_in,
                              void* d_out, int out_size, void* d_ws, size_t ws_size,
                              hipStream_t stream)
{
    const float* x_num = (const float*)d_in[0];
    const int*   x_cat = (const int*)  d_in[1];
    const float* v     = (const float*)d_in[2];
    const float* gb    = (const float*)d_in[3];
    const float* nb    = (const float*)d_in[4];
    const float* cb    = (const float*)d_in[5];
    float*       out   = (float*)d_out;

    const int block = 64;
    const int grid  = (FM_BATCH + block - 1) / block;  // 128 blocks -> spread over CUs
    fm_fwd_kernel<<<grid, block, 0, stream>>>(x_num, x_cat, v, gb, nb, cb, out);
}

// Round 2
// 64.439 us; speedup vs baseline: 1.0033x; 1.0033x over previous
//
#include <hip/hip_runtime.h>

// FM forward on MI355X — 16 lanes per batch row (one lane per emb element).
// Shapes: x_num (8192,3) f32, x_cat (8192,4) i32, v (18183,16) f32,
// global_bias (1,) f32, num_bias (3,) f32, cat_bias (18180,) f32.
// Output: (8192,1) f32.
//
// Math per row b:
//   idx_j = x_cat[b,j] + offset_j, offsets = {0,10000,18000,18100}
//   bias  = gb + sum_j xn_j*nb_j + sum_j cbias[idx_j]
//   s[e]  = sum_j xn_j * v[j,e] + sum_j v[3+idx_j, e]
//   ss[e] = sum_j (xn_j*v[j,e])^2 + sum_j v[3+idx_j,e]^2
//   y = bias + 0.5 * sum_e (s[e]^2 - ss[e])
//
// Layout choice: lane (tid&15) = emb element e -> v loads are contiguous
// 64 B per 16-lane group (coalesced); 16x the parallelism of 1-thread/row
// (2048 waves ~ 8 waves/CU) to hide L2 gather latency.

#define FM_BATCH 8192

__global__ __launch_bounds__(256) void fm_fwd_kernel(
    const float* __restrict__ x_num,
    const int*   __restrict__ x_cat,
    const float* __restrict__ v,
    const float* __restrict__ gbias,
    const float* __restrict__ nbias,
    const float* __restrict__ cbias,
    float*       __restrict__ out)
{
    const int tid = blockIdx.x * blockDim.x + threadIdx.x;
    const int b = tid >> 4;        // batch row
    const int e = tid & 15;        // embedding element
    if (b >= FM_BATCH) return;

    // 16 lanes read the same addresses -> same-address broadcast, 1 transaction
    const float xn0 = x_num[b * 3 + 0];
    const float xn1 = x_num[b * 3 + 1];
    const float xn2 = x_num[b * 3 + 2];

    const int i0 = x_cat[b * 4 + 0];           // + 0
    const int i1 = x_cat[b * 4 + 1] + 10000;
    const int i2 = x_cat[b * 4 + 2] + 18000;
    const int i3 = x_cat[b * 4 + 3] + 18100;

    // numeric rows 0..2 (hot, L1-resident) + 4 gathered categorical rows
    const float a0 = v[0 * 16 + e];
    const float a1 = v[1 * 16 + e];
    const float a2 = v[2 * 16 + e];
    const float c0 = v[(long)(3 + i0) * 16 + e];
    const float c1 = v[(long)(3 + i1) * 16 + e];
    const float c2 = v[(long)(3 + i2) * 16 + e];
    const float c3 = v[(long)(3 + i3) * 16 + e];

    const float t0 = xn0 * a0, t1 = xn1 * a1, t2 = xn2 * a2;
    const float s  = t0 + t1 + t2 + c0 + c1 + c2 + c3;
    const float ss = t0 * t0 + t1 * t1 + t2 * t2
                   + c0 * c0 + c1 * c1 + c2 * c2 + c3 * c3;
    float part = s * s - ss;

    // reduce over the 16 lanes of this row (stays inside the wave)
    part += __shfl_xor(part, 1, 64);
    part += __shfl_xor(part, 2, 64);
    part += __shfl_xor(part, 4, 64);
    part += __shfl_xor(part, 8, 64);

    if (e == 0) {
        const float bias = gbias[0]
                         + xn0 * nbias[0] + xn1 * nbias[1] + xn2 * nbias[2]
                         + cbias[i0] + cbias[i1] + cbias[i2] + cbias[i3];
        out[b] = bias + 0.5f * part;
    }
}

extern "C" void kernel_launch(void* const* d_in, const int* in_sizes, int n_in,
                              void* d_out, int out_size, void* d_ws, size_t ws_size,
                              hipStream_t stream)
{
    const float* x_num = (const float*)d_in[0];
    const int*   x_cat = (const int*)  d_in[1];
    const float* v     = (const float*)d_in[2];
    const float* gb    = (const float*)d_in[3];
    const float* nb    = (const float*)d_in[4];
    const float* cb    = (const float*)d_in[5];
    float*       out   = (float*)d_out;

    const int threads = FM_BATCH * 16;          // 16 lanes per row
    const int block   = 256;
    const int grid    = (threads + block - 1) / block;   // 512 blocks
    fm_fwd_kernel<<<grid, block, 0, stream>>>(x_num, x_cat, v, gb, nb, cb, out);
}